// Round 15
// baseline (98.280 us; speedup 1.0000x reference)
//
#include <hip/hip_runtime.h>
#include <math.h>

typedef unsigned long long u64;
typedef float vf4 __attribute__((ext_vector_type(4)));

constexpr int T_TOTAL = 16777216;          // 2^24
constexpr int TPB     = 256;               // 4 waves per block
constexpr int SEG_W   = 4096;              // elements per wave segment
constexpr int NSEG    = T_TOTAL / SEG_W;   // 4096 segments
constexpr int NBLK    = NSEG / 4;          // 1024 blocks
constexpr int TILE    = 256;               // elements per staged tile
constexpr int NT      = SEG_W / TILE;      // 16 tiles per wave
constexpr float THRESHOLD = 0.5f;

// async global->LDS: no VGPR dest, no implicit wait; lane l's 16 B land at
// ldsbase + 16*l (wave-uniform dst, per-lane src). Counted by vmcnt.
#define GLD16(g, l)                                                           \
    __builtin_amdgcn_global_load_lds(                                         \
        (__attribute__((address_space(1))) void*)(g),                         \
        (__attribute__((address_space(3))) void*)(l), 16, 0, 0)

// Pass 1: per-segment net sums (on/off L3-hot)
__global__ void __launch_bounds__(TPB)
k_segsums(const int2* __restrict__ on2, const int2* __restrict__ off2,
          int* __restrict__ segsums) {
    const int lane = threadIdx.x & 63;
    const int wid  = threadIdx.x >> 6;
    const int seg  = blockIdx.x * 4 + wid;
    const int base = seg * (SEG_W / 2);        // int2 index
    int s = 0;
    #pragma unroll
    for (int g = 0; g < (SEG_W / 2) / 256; ++g) {   // 8 groups
        const int i0 = base + g * 256 + lane;
        int2 a0 = on2[i0];        int2 a1 = on2[i0 + 64];
        int2 a2 = on2[i0 + 128];  int2 a3 = on2[i0 + 192];
        int2 c0 = off2[i0];       int2 c1 = off2[i0 + 64];
        int2 c2 = off2[i0 + 128]; int2 c3 = off2[i0 + 192];
        s += (a0.x + a0.y - c0.x - c0.y) + (a1.x + a1.y - c1.x - c1.y)
           + (a2.x + a2.y - c2.x - c2.y) + (a3.x + a3.y - c3.x - c3.y);
    }
    #pragma unroll
    for (int d = 32; d > 0; d >>= 1) s += __shfl_xor(s, d);
    if (lane == 0) segsums[seg] = s;
}

// Pass 2: exclusive scan of NSEG segment sums (single block, 16/thread)
__global__ void __launch_bounds__(TPB)
k_scan(int* __restrict__ segsums) {
    __shared__ int wsum[4];
    const int lane = threadIdx.x & 63;
    const int wid  = threadIdx.x >> 6;
    int vals[NSEG / TPB];
    const int base = threadIdx.x * (NSEG / TPB);
    int s = 0;
    #pragma unroll
    for (int i = 0; i < NSEG / TPB; i++) { vals[i] = segsums[base + i]; s += vals[i]; }
    int x = s;
    #pragma unroll
    for (int d = 1; d < 64; d <<= 1) {
        int y = __shfl_up(x, d);
        if (lane >= d) x += y;
    }
    if (lane == 63) wsum[wid] = x;
    __syncthreads();
    int wbase = 0;
    #pragma unroll
    for (int w = 0; w < 3; w++) if (w < wid) wbase += wsum[w];
    int ex = wbase + (x - s);
    #pragma unroll
    for (int i = 0; i < NSEG / TPB; i++) { int v = vals[i]; segsums[base + i] = ex; ex += v; }
}

// Per-128-element ballot/popc step (identical math to r6-r14, absmax 0.0)
#define PROC(a, c, uv, ev)                                                    \
    {                                                                         \
        u64 be_on  = __ballot((a).x != 0);                                    \
        u64 bo_on  = __ballot((a).y != 0);                                    \
        u64 be_off = __ballot((c).x != 0);                                    \
        u64 bo_off = __ballot((c).y != 0);                                    \
        const int de = __popcll(be_on & le) - __popcll(be_off & le);          \
        const int pe = basep + de + __popcll(bo_on & lt) - __popcll(bo_off & lt); \
        const int po = basep + de + __popcll(bo_on & le) - __popcll(bo_off & le); \
        basep += __popcll(be_on) - __popcll(be_off)                           \
               + __popcll(bo_on) - __popcll(bo_off);                          \
        const int a0 = pe > 0, a1 = po > 0;                                   \
        cact += a0 + a1;                                                      \
        if (a0 && fabsf((ev)[0] - (uv)[0]) > THRESHOLD) cover++;              \
        if (a1 && fabsf((ev)[2] - (uv)[2]) > THRESHOLD) cover++;              \
    }

// Tile layout in LDS (6144 B): on[0,1024) off[1024,2048) u[2048,4096) e[4096,6144)
#define STAGE(buf, tb)                                                        \
    {                                                                         \
        char* d = (char*)&smem[wid][buf][0];                                  \
        GLD16(on_  + (tb)         + 4 * lane, d);                             \
        GLD16(off_ + (tb)         + 4 * lane, d + 1024);                      \
        GLD16(u_   + 2 * (tb)       + 4 * lane, d + 2048);                    \
        GLD16(u_   + 2 * (tb) + 256 + 4 * lane, d + 3072);                    \
        GLD16(e_   + 2 * (tb)       + 4 * lane, d + 4096);                    \
        GLD16(e_   + 2 * (tb) + 256 + 4 * lane, d + 5120);                    \
    }

// Pass 3: async-DMA double-buffered streaming. Per-wave private buffers, no
// __syncthreads; counted vmcnt(6) keeps next tile's 6 loads in flight (T3/T4).
__global__ void __launch_bounds__(TPB)
k_count(const int* __restrict__ on_, const int* __restrict__ off_,
        const float* __restrict__ u_, const float* __restrict__ e_,
        const int* __restrict__ segpre, int2* __restrict__ partials) {
    __shared__ int4 smem[4][2][384];           // 4 waves x 2 bufs x 6144 B = 48 KB
    const int lane = threadIdx.x & 63;
    const int wid  = threadIdx.x >> 6;
    const int seg  = blockIdx.x * 4 + wid;
    const int sb   = seg * SEG_W;              // element base
    const u64 le = (~0ull) >> (63 - lane);     // lanes 0..i
    const u64 lt = le >> 1;                    // lanes 0..i-1

    int basep = segpre[seg];
    int cover = 0, cact = 0;

    STAGE(0, sb);                              // prologue: tile 0 in flight
    for (int t = 0; t < NT; ++t) {
        const int b = t & 1;
        if (t + 1 < NT) {
            STAGE(b ^ 1, sb + (t + 1) * TILE); // issue next tile first
            __builtin_amdgcn_sched_barrier(0);
            asm volatile("s_waitcnt vmcnt(6)" ::: "memory");  // drain tile t only
        } else {
            asm volatile("s_waitcnt vmcnt(0)" ::: "memory");
        }
        __builtin_amdgcn_sched_barrier(0);

        const char* cur = (const char*)&smem[wid][b][0];
        const int2* onp = (const int2*)cur;
        const int2* ofp = (const int2*)(cur + 1024);
        const vf4*  up  = (const vf4*)(cur + 2048);
        const vf4*  ep  = (const vf4*)(cur + 4096);
        #pragma unroll
        for (int k = 0; k < 2; ++k) {          // 2 x 128 elements
            int2 a  = onp[64 * k + lane];
            int2 c  = ofp[64 * k + lane];
            vf4  uv = up[64 * k + lane];
            vf4  ev = ep[64 * k + lane];
            PROC(a, c, uv, ev);
        }
    }

    #pragma unroll
    for (int d = 32; d > 0; d >>= 1) {
        cover += __shfl_xor(cover, d);
        cact  += __shfl_xor(cact, d);
    }
    __shared__ int sc[4], sa[4];
    if (lane == 0) { sc[wid] = cover; sa[wid] = cact; }
    __syncthreads();
    if (threadIdx.x == 0)
        partials[blockIdx.x] = make_int2(sc[0] + sc[1] + sc[2] + sc[3],
                                         sa[0] + sa[1] + sa[2] + sa[3]);
}

// Pass 4: reduce block partials, divide
__global__ void __launch_bounds__(TPB)
k_final(const int2* __restrict__ partials, float* __restrict__ out) {
    const int lane = threadIdx.x & 63;
    const int wid  = threadIdx.x >> 6;
    int c = 0, a = 0;
    for (int i = threadIdx.x; i < NBLK; i += TPB) {
        int2 p = partials[i];
        c += p.x; a += p.y;
    }
    #pragma unroll
    for (int d = 32; d > 0; d >>= 1) {
        c += __shfl_xor(c, d);
        a += __shfl_xor(a, d);
    }
    __shared__ int sc[4], sa[4];
    if (lane == 0) { sc[wid] = c; sa[wid] = a; }
    __syncthreads();
    if (threadIdx.x == 0) {
        float ctot = (float)(sc[0] + sc[1] + sc[2] + sc[3]);
        float atot = (float)(sa[0] + sa[1] + sa[2] + sa[3]);
        out[0] = ctot / atot;
    }
}

extern "C" void kernel_launch(void* const* d_in, const int* in_sizes, int n_in,
                              void* d_out, int out_size, void* d_ws, size_t ws_size,
                              hipStream_t stream) {
    const float* u   = (const float*)d_in[0];
    const float* e   = (const float*)d_in[1];
    const int*   on  = (const int*)d_in[2];
    const int*   off = (const int*)d_in[3];

    int*  segsums  = (int*)d_ws;                 // NSEG ints (16 KB)
    int2* partials = (int2*)(segsums + NSEG);    // NBLK int2 (8 KB)

    k_segsums<<<NBLK, TPB, 0, stream>>>((const int2*)on, (const int2*)off, segsums);
    k_scan<<<1, TPB, 0, stream>>>(segsums);
    k_count<<<NBLK, TPB, 0, stream>>>(on, off, u, e, segsums, partials);
    k_final<<<1, TPB, 0, stream>>>(partials, (float*)d_out);
}

// Round 17
// 76.536 us; speedup vs baseline: 1.2841x; 1.2841x over previous
//
#include <hip/hip_runtime.h>
#include <math.h>

typedef unsigned long long u64;
typedef float vf4 __attribute__((ext_vector_type(4)));

constexpr int T_TOTAL = 16777216;          // 2^24
constexpr int TPB     = 256;               // 4 waves per block
constexpr int SEG     = 2048;              // elements per wave segment
constexpr int NSEG    = T_TOTAL / SEG;     // 8192 segments
constexpr int NBLK    = NSEG / 4;          // 2048 blocks
constexpr int ITERS   = SEG / 128;         // 16 iterations per wave
constexpr float THRESHOLD = 0.5f;

// ---------------- pass 1: masks + intra-segment prefix bases ----------------
// Reads ONLY on/off (128 MB, L3-resident since u/e bypass L3 via nt).
// Emits per-(seg,iter): 4 ballot words + prefix base, plus segment sums.
// Math validated r10 (absmax 0.0).
#define MPROC(a, c)                                                           \
    {                                                                         \
        u64 pe_ = __ballot((a).x > (c).x);                                    \
        u64 ne_ = __ballot((c).x > (a).x);                                    \
        u64 po_ = __ballot((a).y > (c).y);                                    \
        u64 no_ = __ballot((c).y > (a).y);                                    \
        if (lane == 0) ibases[rec] = ssum;                                    \
        u64 v = pe_;                                                          \
        v = (lane == 1) ? ne_ : v;                                            \
        v = (lane == 2) ? po_ : v;                                            \
        v = (lane == 3) ? no_ : v;                                            \
        if (lane < 4) ballots[(size_t)rec * 4 + lane] = v;                    \
        ssum += __popcll(pe_) - __popcll(ne_) + __popcll(po_) - __popcll(no_);\
        rec++;                                                                \
    }

__global__ void __launch_bounds__(TPB)
k_masks(const int2* __restrict__ on2, const int2* __restrict__ off2,
        u64* __restrict__ ballots, int* __restrict__ ibases,
        int* __restrict__ segsums) {
    const int lane = threadIdx.x & 63;
    const int wid  = threadIdx.x >> 6;
    const int seg  = blockIdx.x * 4 + wid;
    const int base = seg * (SEG / 2);          // int2 index
    int ssum = 0;
    int rec  = seg * ITERS;
    #pragma unroll
    for (int g = 0; g < ITERS / 4; ++g) {
        const int i0 = base + g * 256 + lane;
        int2 a0 = on2[i0];        int2 a1 = on2[i0 + 64];
        int2 a2 = on2[i0 + 128];  int2 a3 = on2[i0 + 192];
        int2 c0 = off2[i0];       int2 c1 = off2[i0 + 64];
        int2 c2 = off2[i0 + 128]; int2 c3 = off2[i0 + 192];
        MPROC(a0, c0);
        MPROC(a1, c1);
        MPROC(a2, c2);
        MPROC(a3, c3);
    }
    if (lane == 0) segsums[seg] = ssum;
}

// ---------------- pass 2: scan of segment sums ----------------
__global__ void __launch_bounds__(TPB)
k_scan(int* __restrict__ segsums) {
    __shared__ int wsum[4];
    const int lane = threadIdx.x & 63;
    const int wid  = threadIdx.x >> 6;
    int vals[NSEG / TPB];
    const int base = threadIdx.x * (NSEG / TPB);
    int s = 0;
    #pragma unroll
    for (int i = 0; i < NSEG / TPB; i++) { vals[i] = segsums[base + i]; s += vals[i]; }
    int x = s;
    #pragma unroll
    for (int d = 1; d < 64; d <<= 1) {
        int y = __shfl_up(x, d);
        if (lane >= d) x += y;
    }
    if (lane == 63) wsum[wid] = x;
    __syncthreads();
    int wbase = 0;
    #pragma unroll
    for (int w = 0; w < 3; w++) if (w < wid) wbase += wsum[w];
    int ex = wbase + (x - s);
    #pragma unroll
    for (int i = 0; i < NSEG / TPB; i++) { int v = vals[i]; segsums[base + i] = ex; ex += v; }
}

// Phase-C step: iteration-independent count from L2-hot ballots
#define PROCC(it, uv, ev)                                                     \
    {                                                                         \
        ulonglong2 w01 = mybb[2 * (it)];       /* pos_e, neg_e */             \
        ulonglong2 w23 = mybb[2 * (it) + 1];   /* pos_o, neg_o */             \
        const int bp = sp + myib[it];                                         \
        const int de = __popcll(w01.x & le) - __popcll(w01.y & le);           \
        const int pe2 = bp + de + __popcll(w23.x & lt) - __popcll(w23.y & lt);\
        const int po2 = bp + de + __popcll(w23.x & le) - __popcll(w23.y & le);\
        const int a0 = pe2 > 0, a1 = po2 > 0;                                 \
        cact += a0 + a1;                                                      \
        if (a0 && fabsf((ev)[0] - (uv)[0]) > THRESHOLD) cover++;              \
        if (a1 && fabsf((ev)[2] - (uv)[2]) > THRESHOLD) cover++;              \
    }

// ---------------- pass 3: clean u/e-only nt streaming ----------------
// No __ballot, no serial chain, only two HBM streams (nt) + L2-hot masks.
__global__ void __launch_bounds__(TPB)
k_count2(const vf4* __restrict__ u4, const vf4* __restrict__ e4,
         const ulonglong2* __restrict__ bb, const int* __restrict__ ibases,
         const int* __restrict__ segpre, int2* __restrict__ partials) {
    const int lane = threadIdx.x & 63;
    const int wid  = threadIdx.x >> 6;
    const int seg  = blockIdx.x * 4 + wid;
    const int base = seg * (SEG / 2);          // float4 index
    const u64 le = (~0ull) >> (63 - lane);     // lanes 0..i
    const u64 lt = le >> 1;                    // lanes 0..i-1

    const int sp = segpre[seg];
    const ulonglong2* mybb = bb + (size_t)seg * ITERS * 2;
    const int* myib = ibases + seg * ITERS;

    int cover = 0, cact = 0;
    #pragma unroll
    for (int g = 0; g < ITERS / 4; ++g) {
        const int i0 = base + g * 256 + lane;
        vf4 u0 = __builtin_nontemporal_load(u4 + i0);
        vf4 u1 = __builtin_nontemporal_load(u4 + i0 + 64);
        vf4 u2 = __builtin_nontemporal_load(u4 + i0 + 128);
        vf4 u3 = __builtin_nontemporal_load(u4 + i0 + 192);
        vf4 e0 = __builtin_nontemporal_load(e4 + i0);
        vf4 e1 = __builtin_nontemporal_load(e4 + i0 + 64);
        vf4 e2 = __builtin_nontemporal_load(e4 + i0 + 128);
        vf4 e3 = __builtin_nontemporal_load(e4 + i0 + 192);
        PROCC(4 * g + 0, u0, e0);
        PROCC(4 * g + 1, u1, e1);
        PROCC(4 * g + 2, u2, e2);
        PROCC(4 * g + 3, u3, e3);
    }

    #pragma unroll
    for (int d = 32; d > 0; d >>= 1) {
        cover += __shfl_xor(cover, d);
        cact  += __shfl_xor(cact, d);
    }
    __shared__ int sc[4], sa[4];
    if (lane == 0) { sc[wid] = cover; sa[wid] = cact; }
    __syncthreads();
    if (threadIdx.x == 0)
        partials[blockIdx.x] = make_int2(sc[0] + sc[1] + sc[2] + sc[3],
                                         sa[0] + sa[1] + sa[2] + sa[3]);
}

// ---------------- fallback path (r14 proven, absmax 0.0) ----------------
__global__ void __launch_bounds__(TPB)
k_segsums(const int2* __restrict__ on2, const int2* __restrict__ off2,
          int* __restrict__ segsums) {
    const int lane = threadIdx.x & 63;
    const int wid  = threadIdx.x >> 6;
    const int seg  = blockIdx.x * 4 + wid;
    const int base = seg * (SEG / 2);
    int s = 0;
    #pragma unroll
    for (int g = 0; g < ITERS / 4; ++g) {
        const int i0 = base + g * 256 + lane;
        int2 a0 = on2[i0];        int2 a1 = on2[i0 + 64];
        int2 a2 = on2[i0 + 128];  int2 a3 = on2[i0 + 192];
        int2 c0 = off2[i0];       int2 c1 = off2[i0 + 64];
        int2 c2 = off2[i0 + 128]; int2 c3 = off2[i0 + 192];
        s += (a0.x + a0.y - c0.x - c0.y) + (a1.x + a1.y - c1.x - c1.y)
           + (a2.x + a2.y - c2.x - c2.y) + (a3.x + a3.y - c3.x - c3.y);
    }
    #pragma unroll
    for (int d = 32; d > 0; d >>= 1) s += __shfl_xor(s, d);
    if (lane == 0) segsums[seg] = s;
}

#define PROC(a, c, uv, ev)                                                    \
    {                                                                         \
        u64 be_on  = __ballot((a).x != 0);                                    \
        u64 bo_on  = __ballot((a).y != 0);                                    \
        u64 be_off = __ballot((c).x != 0);                                    \
        u64 bo_off = __ballot((c).y != 0);                                    \
        const int de = __popcll(be_on & le) - __popcll(be_off & le);          \
        const int pe = basep + de + __popcll(bo_on & lt) - __popcll(bo_off & lt); \
        const int po = basep + de + __popcll(bo_on & le) - __popcll(bo_off & le); \
        basep += __popcll(be_on) - __popcll(be_off)                           \
               + __popcll(bo_on) - __popcll(bo_off);                          \
        const int a0 = pe > 0, a1 = po > 0;                                   \
        cact += a0 + a1;                                                      \
        if (a0 && fabsf((ev)[0] - (uv)[0]) > THRESHOLD) cover++;              \
        if (a1 && fabsf((ev)[2] - (uv)[2]) > THRESHOLD) cover++;              \
    }

__global__ void __launch_bounds__(TPB)
k_count(const int2* __restrict__ on2, const int2* __restrict__ off2,
        const vf4* __restrict__ u4, const vf4* __restrict__ e4,
        const int* __restrict__ segpre, int2* __restrict__ partials) {
    const int lane = threadIdx.x & 63;
    const int wid  = threadIdx.x >> 6;
    const int seg  = blockIdx.x * 4 + wid;
    const int base = seg * (SEG / 2);
    const u64 le = (~0ull) >> (63 - lane);
    const u64 lt = le >> 1;
    int basep = segpre[seg];
    int cover = 0, cact = 0;
    #pragma unroll
    for (int g = 0; g < ITERS / 4; ++g) {
        const int i0 = base + g * 256 + lane;
        int2 a0 = on2[i0];        int2 a1 = on2[i0 + 64];
        int2 a2 = on2[i0 + 128];  int2 a3 = on2[i0 + 192];
        int2 c0 = off2[i0];       int2 c1 = off2[i0 + 64];
        int2 c2 = off2[i0 + 128]; int2 c3 = off2[i0 + 192];
        vf4 u0 = __builtin_nontemporal_load(u4 + i0);
        vf4 u1 = __builtin_nontemporal_load(u4 + i0 + 64);
        vf4 u2 = __builtin_nontemporal_load(u4 + i0 + 128);
        vf4 u3 = __builtin_nontemporal_load(u4 + i0 + 192);
        vf4 e0 = __builtin_nontemporal_load(e4 + i0);
        vf4 e1 = __builtin_nontemporal_load(e4 + i0 + 64);
        vf4 e2 = __builtin_nontemporal_load(e4 + i0 + 128);
        vf4 e3 = __builtin_nontemporal_load(e4 + i0 + 192);
        PROC(a0, c0, u0, e0);
        PROC(a1, c1, u1, e1);
        PROC(a2, c2, u2, e2);
        PROC(a3, c3, u3, e3);
    }
    #pragma unroll
    for (int d = 32; d > 0; d >>= 1) {
        cover += __shfl_xor(cover, d);
        cact  += __shfl_xor(cact, d);
    }
    __shared__ int sc[4], sa[4];
    if (lane == 0) { sc[wid] = cover; sa[wid] = cact; }
    __syncthreads();
    if (threadIdx.x == 0)
        partials[blockIdx.x] = make_int2(sc[0] + sc[1] + sc[2] + sc[3],
                                         sa[0] + sa[1] + sa[2] + sa[3]);
}

// ---------------- final reduce ----------------
__global__ void __launch_bounds__(TPB)
k_final(const int2* __restrict__ partials, float* __restrict__ out) {
    const int lane = threadIdx.x & 63;
    const int wid  = threadIdx.x >> 6;
    int c = 0, a = 0;
    for (int i = threadIdx.x; i < NBLK; i += TPB) {
        int2 p = partials[i];
        c += p.x; a += p.y;
    }
    #pragma unroll
    for (int d = 32; d > 0; d >>= 1) {
        c += __shfl_xor(c, d);
        a += __shfl_xor(a, d);
    }
    __shared__ int sc[4], sa[4];
    if (lane == 0) { sc[wid] = c; sa[wid] = a; }
    __syncthreads();
    if (threadIdx.x == 0) {
        float ctot = (float)(sc[0] + sc[1] + sc[2] + sc[3]);
        float atot = (float)(sa[0] + sa[1] + sa[2] + sa[3]);
        out[0] = ctot / atot;
    }
}

extern "C" void kernel_launch(void* const* d_in, const int* in_sizes, int n_in,
                              void* d_out, int out_size, void* d_ws, size_t ws_size,
                              hipStream_t stream) {
    const float* u   = (const float*)d_in[0];
    const float* e   = (const float*)d_in[1];
    const int*   on  = (const int*)d_in[2];
    const int*   off = (const int*)d_in[3];

    int*  segsums  = (int*)d_ws;                          // 32 KB
    int2* partials = (int2*)(segsums + NSEG);             // 16 KB
    int*  ibases   = (int*)((char*)d_ws + 48 * 1024);     // 512 KB
    u64*  ballots  = (u64*)((char*)d_ws + 560 * 1024);    // 4 MB

    const size_t need = 560 * 1024 + (size_t)NSEG * ITERS * 4 * sizeof(u64);

    if (ws_size >= need) {
        k_masks<<<NBLK, TPB, 0, stream>>>((const int2*)on, (const int2*)off,
                                          ballots, ibases, segsums);
        k_scan<<<1, TPB, 0, stream>>>(segsums);
        k_count2<<<NBLK, TPB, 0, stream>>>((const vf4*)u, (const vf4*)e,
                                           (const ulonglong2*)ballots, ibases,
                                           segsums, partials);
    } else {
        k_segsums<<<NBLK, TPB, 0, stream>>>((const int2*)on, (const int2*)off, segsums);
        k_scan<<<1, TPB, 0, stream>>>(segsums);
        k_count<<<NBLK, TPB, 0, stream>>>((const int2*)on, (const int2*)off,
                                          (const vf4*)u, (const vf4*)e,
                                          segsums, partials);
    }
    k_final<<<1, TPB, 0, stream>>>(partials, (float*)d_out);
}